// Round 12
// baseline (246.667 us; speedup 1.0000x reference)
//
#include <hip/hip_runtime.h>
#include <hip/hip_bf16.h>
#include <cstdint>
#include <cstddef>

// Problem constants
#define Bsz 4
#define Tsz 8192
#define Dsz 512
#define Hn 8
#define BSn 16
#define NBn 512     // T/BS blocks (attention sequence length)
#define DHn 64      // head dim
#define NQKV 1536   // 3*D
#define MROWS 32768 // B*T

// softmax scale folded with log2(e), applied to Q at gemm epilogue
#define SCL 0.06375870136f
// fixed softmax max (exp2 domain); constant offset cancels in p/sum(p)
#define ATT_M 8.0f

typedef __attribute__((ext_vector_type(8))) short short8;
typedef __attribute__((ext_vector_type(4))) short short4v;
typedef __attribute__((ext_vector_type(4))) float float4f;

__device__ __forceinline__ uint16_t f2b(float f) {
  union { float f; uint32_t u; } v; v.f = f;
  uint32_t u = v.u;
  return (uint16_t)((u + 0x7fffu + ((u >> 16) & 1u)) >> 16);  // RNE
}

// pack two f32 -> (bf16(b)<<16)|bf16(a), round-half-up (bias ~2^-17, negligible)
__device__ __forceinline__ uint32_t pk2(float a, float b) {
  union { float f; uint32_t u; } x, y; x.f = a; y.f = b;
  return __builtin_amdgcn_perm(y.u + 0x8000u, x.u + 0x8000u, 0x07060302u);
}

// truncating variant (softmax P only; l sums the same raw p so it stays consistent)
__device__ __forceinline__ uint32_t pk2t(float a, float b) {
  union { float f; uint32_t u; } x, y; x.f = a; y.f = b;
  return __builtin_amdgcn_perm(y.u, x.u, 0x07060302u);
}

// async 16B global -> LDS (wave-uniform LDS base + lane*16)
__device__ __forceinline__ void gl_lds16(const void* g, void* l) {
  __builtin_amdgcn_global_load_lds(
      (const __attribute__((address_space(1))) unsigned int*)g,
      (__attribute__((address_space(3))) unsigned int*)l, 16, 0, 0);
}

// ---------------- fused convert kernel (x and Wq/Wk/Wv -> bf16) ----------------
// Fusion verdict (r4/r5/r6, measured): with a 64-AGPR accumulator there is no
// register/schedule window where in-gemm f32->bf16 A conversion beats this
// separate memory-bound pass (92 vs 106 vs 116 us). This pass runs at ~6.3 TB/s.
#define XBLK (MROWS * Dsz / 1024)   // 16384 blocks for x
__global__ void cvt_kernel(const float* __restrict__ x, const float* __restrict__ Wq,
                           const float* __restrict__ Wk, const float* __restrict__ Wv,
                           uint16_t* __restrict__ xb, uint16_t* __restrict__ wc) {
  int bid = blockIdx.x;
  if (bid < XBLK) {
    int i = (bid * 256 + threadIdx.x) * 4;
    float4 v = *(const float4*)(x + i);
    uint64_t o = (uint64_t)pk2(v.x, v.y) | ((uint64_t)pk2(v.z, v.w) << 32);
    *(uint64_t*)(xb + i) = o;
  } else {
    int i = ((bid - XBLK) * 256 + threadIdx.x) * 4;  // i < 1536*512
    int row = i >> 9;
    int col = i & 511;
    const float* src = (row < 512) ? Wq : ((row < 1024) ? Wk : Wv);
    float4 v = *(const float4*)(src + (size_t)(row & 511) * 512 + col);
    uint64_t o = (uint64_t)pk2(v.x, v.y) | ((uint64_t)pk2(v.z, v.w) << 32);
    *(uint64_t*)(wc + i) = o;
  }
}

// ---------------- QKV projection GEMM ----------------
// Y[M=32768, N=1536] = Xb[M,512] * Wc[N,512]^T + bias.
// 2-phase 128x128 structure (r1/r3/r11 verified: 61-63 us, at the documented
// ceiling of this structure for K=512; 8-phase regressed in r0).
#define BM 128
#define BN 128
#define BK 64

__global__ __launch_bounds__(256, 4) void gemm_qkv(
    const uint16_t* __restrict__ Xb, const uint16_t* __restrict__ Wc,
    const float* __restrict__ bq, const float* __restrict__ bkp,
    const float* __restrict__ bv, uint16_t* __restrict__ Qp,
    uint16_t* __restrict__ Kp, uint16_t* __restrict__ Vtmp) {
  __shared__ uint16_t As[BM * BK];  // 16KB, row=64 elems=8 chunks, pos = c ^ (row&7)
  __shared__ uint16_t Bs[BN * BK];  // 16KB
  const int tid = threadIdx.x;
  const int wave = tid >> 6, lane = tid & 63;
  const int lrow = lane & 15, quad = lane >> 4;

  // XCD swizzle: 12 n-blocks of one m-slice stay consecutive on one XCD.
  int g = blockIdx.x;
  int xcd = g & 7, ii = g >> 3;        // ii in [0,384)
  int mt = xcd * 32 + ii / 12;
  int nt = ii - (ii / 12) * 12;
  const int m0 = mt * BM;
  const int n0 = nt * BN;
  const int wm = (wave >> 1) * 64, wn = (wave & 1) * 64;  // wave tile 64m x 64n

  float4f acc[4][4] = {};   // [i: m-subtile][j: n-subtile]

  for (int k0 = 0; k0 < Dsz; k0 += BK) {
    __syncthreads();
#pragma unroll
    for (int p = 0; p < 4; ++p) {       // As: 1024 chunks
      int cbase = p * 256 + wave * 64;
      int c = cbase + lane;
      int row = c >> 3, pos = c & 7;
      int kc = (pos ^ (row & 7)) * 8;   // swizzle on the GLOBAL side (free)
      gl_lds16(Xb + (size_t)(m0 + row) * Dsz + k0 + kc, As + cbase * 8);
    }
#pragma unroll
    for (int p = 0; p < 4; ++p) {       // Bs: 1024 chunks
      int cbase = p * 256 + wave * 64;
      int c = cbase + lane;
      int row = c >> 3, pos = c & 7;
      int kc = (pos ^ (row & 7)) * 8;
      gl_lds16(Wc + (size_t)(n0 + row) * Dsz + k0 + kc, Bs + cbase * 8);
    }
    __syncthreads();

#pragma unroll
    for (int h = 0; h < 2; ++h) {
      short8 af[4], bf[4];
#pragma unroll
      for (int i = 0; i < 4; ++i) {
        int rowA = wm + i * 16 + lrow;
        af[i] = *(const short8*)(As + rowA * BK + (((h * 4 + quad) ^ (rowA & 7)) * 8));
      }
#pragma unroll
      for (int j = 0; j < 4; ++j) {
        int rowB = wn + j * 16 + lrow;
        bf[j] = *(const short8*)(Bs + rowB * BK + (((h * 4 + quad) ^ (rowB & 7)) * 8));
      }
#pragma unroll
      for (int i = 0; i < 4; ++i)
#pragma unroll
        for (int j = 0; j < 4; ++j)
          acc[i][j] = __builtin_amdgcn_mfma_f32_16x16x32_bf16(af[i], bf[j], acc[i][j], 0, 0, 0);
    }
  }

  // epilogue: token s = quad*4+r, dh consecutive over lrow
  const int region = n0 >> 9;  // 0=Q, 1=K, 2=V (128 | 512 so no tile crosses)
  const float* bias = (region == 0) ? bq : ((region == 1) ? bkp : bv);
  const float mult = (region == 0) ? SCL : 1.0f;
  const int bb = m0 >> 13;
  const int nbbase = ((m0 & 8191) >> 4) + (wm >> 4);    // nb = nbbase + i
  const int nv0 = (n0 & 511) + wn;

  if (region < 2) {
    uint16_t* dst = (region == 0) ? Qp : Kp;
#pragma unroll
    for (int j = 0; j < 4; ++j) {
      int nl = nv0 + j * 16 + lrow;
      int hh = nl >> 6, dh = nl & 63;
      float bval = bias[nl];
      // addr = ((b*16+s)*8+h)*32768 + nb*64 + dh  (s = quad*4+r)
      size_t base = (size_t)bb * 4194304 + (size_t)hh * 32768 +
                    (size_t)nbbase * 64 + dh + (size_t)(quad * 4) * 262144;
#pragma unroll
      for (int i = 0; i < 4; ++i)
#pragma unroll
        for (int r = 0; r < 4; ++r)
          dst[base + (size_t)r * 262144 + (size_t)i * 64] =
              f2b((acc[i][j][r] + bval) * mult);
    }
  } else {
#pragma unroll
    for (int j = 0; j < 4; ++j) {
      int nl = nv0 + j * 16 + lrow;
      float bval = bias[nl];
#pragma unroll
      for (int i = 0; i < 4; ++i) {
        int tok = m0 + wm + i * 16 + quad * 4;
#pragma unroll
        for (int r = 0; r < 4; ++r)
          Vtmp[(size_t)(tok + r) * 512 + nl] = f2b(acc[i][j][r] + bval);
      }
    }
  }
}

// ---------------- fused block attention, S^T orientation, fixed-max softmax ----------------
// r12: 2-wave (128-thread) blocks, grid 2048. r11 diagnosis: attn is
// latency/packing-bound (MfmaUtil 20.9 + VALUBusy 25, occupancy 21.5%) --
// grid 1024 at 3 blocks/CU runs per-CU as 3-concurrent + 1-alone = 2.0
// block-times. Halving the block (same per-wave work, SAME register
// footprint -- r7 proved 4/CU spills) packs 6 x 24KB blocks/CU -> 8 blocks
// drain in ~1.33 block-times. K/V tiles (2048 elems) staged in TWO gl_lds
// passes (pass p covers chunks p*128+tid; source mapping identical to r11's
// 256-thread pass, e_hi=p). XCD swizzle: all 4 q-quarters of one (b,s,h)
// on one XCD -> K/V re-reads L2-local.
__global__ __launch_bounds__(128, 3) void attn_kernel(
    const uint16_t* __restrict__ Qp, const uint16_t* __restrict__ Kp,
    const uint16_t* __restrict__ Vtmp, float* __restrict__ out) {
  __shared__ uint16_t Ks[2][32 * 64];     // K tile, rows 128B, chunk pos = c ^ (r&7)
  __shared__ uint16_t Vs[2][32 * 64];     // V tile in tr-subtiled layout
  __shared__ uint16_t Ps[2][4][16 * 32];  // [wave][qs] P [q][kv], pos = c ^ ((q>>1)&3)

  // XCD swizzle decode: 2048 = 8 XCD x 64 bsh x 4 qq
  int g = blockIdx.x;
  const int xcd = g & 7;
  const int ii = g >> 3;                 // [0,256)
  const int bsh = xcd * 64 + (ii >> 2);
  const int qq = ii & 3;
  const int h = bsh & 7;
  const int s = (bsh >> 3) & 15;
  const int b = bsh >> 7;

  const int tid = threadIdx.x;           // < 128
  const int w = tid >> 6, lane = tid & 63;
  const int lrow = lane & 15, quad = lane >> 4;

  const size_t sh = (((size_t)b * 16 + s) * 8 + h);
  const uint16_t* Qb = Qp + (sh << 15);   // [512 nb][64 dh]
  const uint16_t* Kb = Kp + (sh << 15);   // [512 nb][64 dh]

  // V staging source (two passes p; chunk c = p*128 + tid covers LDS elems
  // [8c,8c+8) of the tr layout): kv = qv*8 + p*4 + jv, dh_base = dt*16 + hb*8.
  const int dtv = (tid >> 5) & 3, qv = (tid >> 3) & 3,
            jv = (tid >> 1) & 3, hbv = tid & 1;
  const uint16_t* vbase = Vtmp + ((size_t)b * Tsz + s) * 512 + h * 64 +
                          dtv * 16 + hbv * 8;
  const uint16_t* vsrc0 = vbase + (size_t)(qv * 8 + jv) * 8192;
  const uint16_t* vsrc1 = vbase + (size_t)(qv * 8 + 4 + jv) * 8192;
  const unsigned vs_base =
      (unsigned)(uintptr_t)(__attribute__((address_space(3))) const uint16_t*)&Vs[0][0];

  // K staging: pass p stages rows p*16 + w*8 + (lane>>3); (row&7) invariant in p
  const int kr0 = w * 8 + (lane >> 3);
  const int kcs = (lane & 7) ^ (kr0 & 7);

  // Q B-fragments (persistent): 4 q-subtiles x 2 dh-chunks; wave owns 64 q rows
  short8 qB[4][2];
  const int q0 = qq * 128 + w * 64;
#pragma unroll
  for (int qs = 0; qs < 4; ++qs) {
    const uint16_t* qp = Qb + (size_t)(q0 + qs * 16 + lrow) * 64;
    qB[qs][0] = *(const short8*)(qp + quad * 8);
    qB[qs][1] = *(const short8*)(qp + 32 + quad * 8);
  }

  float4f O[4][4] = {};                 // [dh tile][q subtile], C-layout (col=q)
  float l_acc[4] = {0.f, 0.f, 0.f, 0.f};

  const int sw = (lrow >> 1) & 3;
  const float4f negm = {-ATT_M, -ATT_M, -ATT_M, -ATT_M};

#define ATT_STAGE(buf, kv0_) do {                                              \
    gl_lds16(Kb + (size_t)((kv0_) + kr0) * 64 + kcs * 8, &Ks[buf][w * 512]);   \
    gl_lds16(Kb + (size_t)((kv0_) + kr0 + 16) * 64 + kcs * 8,                  \
             &Ks[buf][1024 + w * 512]);                                        \
    gl_lds16(vsrc0 + (size_t)(kv0_) * 8192, &Vs[buf][w * 512]);                \
    gl_lds16(vsrc1 + (size_t)(kv0_) * 8192, &Vs[buf][1024 + w * 512]);         \
  } while (0)

  ATT_STAGE(0, 0);
  __syncthreads();

  for (int it = 0; it < 16; ++it) {
    const int cur = it & 1;
    if (it < 15) ATT_STAGE(cur ^ 1, (it + 1) * 32);  // prefetch hides under compute

    // ---- S-phase: K A-fragments, scores, exp2, pack into Ps ----
    {
      short8 kA[2][2];
#pragma unroll
      for (int kt = 0; kt < 2; ++kt) {
        int row = kt * 16 + lrow;
#pragma unroll
        for (int kc = 0; kc < 2; ++kc) {
          int cc = (kc * 4 + quad) ^ (row & 7);
          kA[kt][kc] = *(const short8*)(&Ks[cur][row * 64 + cc * 8]);
        }
      }
#pragma unroll
      for (int qs = 0; qs < 4; ++qs) {
        // C pre-loaded with -M: exp2 args come out of MFMA directly
        float4f c0 = negm, c1 = negm;
        __builtin_amdgcn_s_setprio(1);
        c0 = __builtin_amdgcn_mfma_f32_16x16x32_bf16(kA[0][0], qB[qs][0], c0, 0, 0, 0);
        c0 = __builtin_amdgcn_mfma_f32_16x16x32_bf16(kA[0][1], qB[qs][1], c0, 0, 0, 0);
        c1 = __builtin_amdgcn_mfma_f32_16x16x32_bf16(kA[1][0], qB[qs][0], c1, 0, 0, 0);
        c1 = __builtin_amdgcn_mfma_f32_16x16x32_bf16(kA[1][1], qB[qs][1], c1, 0, 0, 0);
        __builtin_amdgcn_s_setprio(0);

        float p00 = __builtin_amdgcn_exp2f(c0[0]);
        float p01 = __builtin_amdgcn_exp2f(c0[1]);
        float p02 = __builtin_amdgcn_exp2f(c0[2]);
        float p03 = __builtin_amdgcn_exp2f(c0[3]);
        float p10 = __builtin_amdgcn_exp2f(c1[0]);
        float p11 = __builtin_amdgcn_exp2f(c1[1]);
        float p12 = __builtin_amdgcn_exp2f(c1[2]);
        float p13 = __builtin_amdgcn_exp2f(c1[3]);
        l_acc[qs] += ((p00 + p01) + (p02 + p03)) + ((p10 + p11) + (p12 + p13));

        uint32_t d0 = pk2t(p00, p01), d1 = pk2t(p02, p03);
        uint32_t d2 = pk2t(p10, p11), d3 = pk2t(p12, p13);
        uint16_t* Psq = Ps[w][qs];
        int half = (quad & 1) * 4;
        *(uint2*)(Psq + lrow * 32 + (((quad >> 1)) ^ sw) * 8 + half) = make_uint2(d0, d1);
        *(uint2*)(Psq + lrow * 32 + ((2 + (quad >> 1)) ^ sw) * 8 + half) = make_uint2(d2, d3);
      }
    }

    // ---- PV-phase: V^T A-fragments via hardware transpose read ----
    {
      short4v t0, t1, t2, t3, t4, t5, t6, t7;
      unsigned vaddr = vs_base + (cur << 12) + (lane << 3);
      asm volatile(
          "ds_read_b64_tr_b16 %0, %8\n\t"
          "ds_read_b64_tr_b16 %1, %8 offset:2048\n\t"
          "ds_read_b64_tr_b16 %2, %8 offset:512\n\t"
          "ds_read_b64_tr_b16 %3, %8 offset:2560\n\t"
          "ds_read_b64_tr_b16 %4, %8 offset:1024\n\t"
          "ds_read_b64_tr_b16 %5, %8 offset:3072\n\t"
          "ds_read_b64_tr_b16 %6, %8 offset:1536\n\t"
          "ds_read_b64_tr_b16 %7, %8 offset:3584\n\t"
          "s_waitcnt lgkmcnt(0)"
          : "=&v"(t0), "=&v"(t1), "=&v"(t2), "=&v"(t3),
            "=&v"(t4), "=&v"(t5), "=&v"(t6), "=&v"(t7)
          : "v"(vaddr));
      __builtin_amdgcn_sched_barrier(0);
      short8 vA[4];
      vA[0] = __builtin_shufflevector(t0, t1, 0, 1, 2, 3, 4, 5, 6, 7);
      vA[1] = __builtin_shufflevector(t2, t3, 0, 1, 2, 3, 4, 5, 6, 7);
      vA[2] = __builtin_shufflevector(t4, t5, 0, 1, 2, 3, 4, 5, 6, 7);
      vA[3] = __builtin_shufflevector(t6, t7, 0, 1, 2, 3, 4, 5, 6, 7);
#pragma unroll
      for (int qs = 0; qs < 4; ++qs) {
        short8 pB = *(const short8*)(Ps[w][qs] + lrow * 32 + (quad ^ sw) * 8);
        __builtin_amdgcn_s_setprio(1);
#pragma unroll
        for (int dt = 0; dt < 4; ++dt)
          O[dt][qs] = __builtin_amdgcn_mfma_f32_16x16x32_bf16(vA[dt], pB, O[dt][qs], 0, 0, 0);
        __builtin_amdgcn_s_setprio(0);
      }
    }

    if (it < 15) __syncthreads();  // own stage landed (vmcnt) + all waves done with cur
  }
#undef ATT_STAGE

  // epilogue: reduce l across quads (kv partials), normalize, write fp32
#pragma unroll
  for (int qs = 0; qs < 4; ++qs) {
    float l = l_acc[qs];
    l += __shfl_xor(l, 16);
    l += __shfl_xor(l, 32);
    float inv = 1.0f / l;
    int qg = q0 + qs * 16 + lrow;   // nb index of this lane's q column
    float* op = out + ((size_t)b * Tsz + (size_t)qg * 16 + s) * Dsz + h * 64;
#pragma unroll
    for (int dt = 0; dt < 4; ++dt) {
      float4 vv;
      vv.x = O[dt][qs][0] * inv; vv.y = O[dt][qs][1] * inv;
      vv.z = O[dt][qs][2] * inv; vv.w = O[dt][qs][3] * inv;
      *(float4*)(op + dt * 16 + quad * 4) = vv;
    }
  }
}

// ---------------- launch ----------------
extern "C" void kernel_launch(void* const* d_in, const int* in_sizes, int n_in,
                              void* d_out, int out_size, void* d_ws, size_t ws_size,
                              hipStream_t stream) {
  const float* x  = (const float*)d_in[0];
  const float* Wq = (const float*)d_in[1];
  const float* bq = (const float*)d_in[2];
  const float* Wk = (const float*)d_in[3];
  const float* bk = (const float*)d_in[4];
  const float* Wv = (const float*)d_in[5];
  const float* bv = (const float*)d_in[6];
  float* out = (float*)d_out;

  // workspace: Qp | Kp | Vtmp | xb | wc
  uint16_t* Qp   = (uint16_t*)d_ws;
  uint16_t* Kp   = Qp + (size_t)16777216;
  uint16_t* Vtmp = Kp + (size_t)16777216;
  uint16_t* xb   = Vtmp + (size_t)16777216;
  uint16_t* wc   = xb + (size_t)16777216;

  hipLaunchKernelGGL(cvt_kernel, dim3(XBLK + NQKV * Dsz / 1024), dim3(256), 0, stream,
                     x, Wq, Wk, Wv, xb, wc);
  hipLaunchKernelGGL(gemm_qkv, dim3((MROWS / BM) * (NQKV / BN)), dim3(256), 0, stream,
                     xb, wc, bq, bk, bv, Qp, Kp, Vtmp);
  hipLaunchKernelGGL(attn_kernel, dim3(Bsz * BSn * Hn * 4), dim3(128), 0, stream,
                     Qp, Kp, Vtmp, out);
}

// Round 13
// 233.009 us; speedup vs baseline: 1.0586x; 1.0586x over previous
//
#include <hip/hip_runtime.h>
#include <hip/hip_bf16.h>
#include <cstdint>
#include <cstddef>

// Problem constants
#define Bsz 4
#define Tsz 8192
#define Dsz 512
#define Hn 8
#define BSn 16
#define NBn 512     // T/BS blocks (attention sequence length)
#define DHn 64      // head dim
#define NQKV 1536   // 3*D
#define MROWS 32768 // B*T

// softmax scale folded with log2(e), applied to Q at gemm epilogue
#define SCL 0.06375870136f
// fixed softmax max (exp2 domain); constant offset cancels in p/sum(p)
#define ATT_M 8.0f

typedef __attribute__((ext_vector_type(8))) short short8;
typedef __attribute__((ext_vector_type(4))) short short4v;
typedef __attribute__((ext_vector_type(4))) float float4f;

__device__ __forceinline__ uint16_t f2b(float f) {
  union { float f; uint32_t u; } v; v.f = f;
  uint32_t u = v.u;
  return (uint16_t)((u + 0x7fffu + ((u >> 16) & 1u)) >> 16);  // RNE
}

// pack two f32 -> (bf16(b)<<16)|bf16(a), round-half-up (bias ~2^-17, negligible)
__device__ __forceinline__ uint32_t pk2(float a, float b) {
  union { float f; uint32_t u; } x, y; x.f = a; y.f = b;
  return __builtin_amdgcn_perm(y.u + 0x8000u, x.u + 0x8000u, 0x07060302u);
}

// truncating variant (softmax P only; l sums the same raw p so it stays consistent)
__device__ __forceinline__ uint32_t pk2t(float a, float b) {
  union { float f; uint32_t u; } x, y; x.f = a; y.f = b;
  return __builtin_amdgcn_perm(y.u, x.u, 0x07060302u);
}

// async 16B global -> LDS (wave-uniform LDS base + lane*16)
__device__ __forceinline__ void gl_lds16(const void* g, void* l) {
  __builtin_amdgcn_global_load_lds(
      (const __attribute__((address_space(1))) unsigned int*)g,
      (__attribute__((address_space(3))) unsigned int*)l, 16, 0, 0);
}

// ---------------- fused convert kernel (x and Wq/Wk/Wv -> bf16) ----------------
// Fusion verdict (r4/r5/r6, measured): with a 64-AGPR accumulator there is no
// register/schedule window where in-gemm f32->bf16 A conversion beats this
// separate memory-bound pass (92 vs 106 vs 116 us). This pass runs at ~6.3 TB/s.
#define XBLK (MROWS * Dsz / 1024)   // 16384 blocks for x
__global__ void cvt_kernel(const float* __restrict__ x, const float* __restrict__ Wq,
                           const float* __restrict__ Wk, const float* __restrict__ Wv,
                           uint16_t* __restrict__ xb, uint16_t* __restrict__ wc) {
  int bid = blockIdx.x;
  if (bid < XBLK) {
    int i = (bid * 256 + threadIdx.x) * 4;
    float4 v = *(const float4*)(x + i);
    uint64_t o = (uint64_t)pk2(v.x, v.y) | ((uint64_t)pk2(v.z, v.w) << 32);
    *(uint64_t*)(xb + i) = o;
  } else {
    int i = ((bid - XBLK) * 256 + threadIdx.x) * 4;  // i < 1536*512
    int row = i >> 9;
    int col = i & 511;
    const float* src = (row < 512) ? Wq : ((row < 1024) ? Wk : Wv);
    float4 v = *(const float4*)(src + (size_t)(row & 511) * 512 + col);
    uint64_t o = (uint64_t)pk2(v.x, v.y) | ((uint64_t)pk2(v.z, v.w) << 32);
    *(uint64_t*)(wc + i) = o;
  }
}

// ---------------- QKV projection GEMM ----------------
// Y[M=32768, N=1536] = Xb[M,512] * Wc[N,512]^T + bias.
// 2-phase 128x128 structure (r1/r3/r11 verified: 61-63 us, at the documented
// ceiling of this structure for K=512; 8-phase regressed in r0).
#define BM 128
#define BN 128
#define BK 64

__global__ __launch_bounds__(256, 4) void gemm_qkv(
    const uint16_t* __restrict__ Xb, const uint16_t* __restrict__ Wc,
    const float* __restrict__ bq, const float* __restrict__ bkp,
    const float* __restrict__ bv, uint16_t* __restrict__ Qp,
    uint16_t* __restrict__ Kp, uint16_t* __restrict__ Vtmp) {
  __shared__ uint16_t As[BM * BK];  // 16KB, row=64 elems=8 chunks, pos = c ^ (row&7)
  __shared__ uint16_t Bs[BN * BK];  // 16KB
  const int tid = threadIdx.x;
  const int wave = tid >> 6, lane = tid & 63;
  const int lrow = lane & 15, quad = lane >> 4;

  // XCD swizzle: 12 n-blocks of one m-slice stay consecutive on one XCD.
  int g = blockIdx.x;
  int xcd = g & 7, ii = g >> 3;        // ii in [0,384)
  int mt = xcd * 32 + ii / 12;
  int nt = ii - (ii / 12) * 12;
  const int m0 = mt * BM;
  const int n0 = nt * BN;
  const int wm = (wave >> 1) * 64, wn = (wave & 1) * 64;  // wave tile 64m x 64n

  float4f acc[4][4] = {};   // [i: m-subtile][j: n-subtile]

  for (int k0 = 0; k0 < Dsz; k0 += BK) {
    __syncthreads();
#pragma unroll
    for (int p = 0; p < 4; ++p) {       // As: 1024 chunks
      int cbase = p * 256 + wave * 64;
      int c = cbase + lane;
      int row = c >> 3, pos = c & 7;
      int kc = (pos ^ (row & 7)) * 8;   // swizzle on the GLOBAL side (free)
      gl_lds16(Xb + (size_t)(m0 + row) * Dsz + k0 + kc, As + cbase * 8);
    }
#pragma unroll
    for (int p = 0; p < 4; ++p) {       // Bs: 1024 chunks
      int cbase = p * 256 + wave * 64;
      int c = cbase + lane;
      int row = c >> 3, pos = c & 7;
      int kc = (pos ^ (row & 7)) * 8;
      gl_lds16(Wc + (size_t)(n0 + row) * Dsz + k0 + kc, Bs + cbase * 8);
    }
    __syncthreads();

#pragma unroll
    for (int h = 0; h < 2; ++h) {
      short8 af[4], bf[4];
#pragma unroll
      for (int i = 0; i < 4; ++i) {
        int rowA = wm + i * 16 + lrow;
        af[i] = *(const short8*)(As + rowA * BK + (((h * 4 + quad) ^ (rowA & 7)) * 8));
      }
#pragma unroll
      for (int j = 0; j < 4; ++j) {
        int rowB = wn + j * 16 + lrow;
        bf[j] = *(const short8*)(Bs + rowB * BK + (((h * 4 + quad) ^ (rowB & 7)) * 8));
      }
#pragma unroll
      for (int i = 0; i < 4; ++i)
#pragma unroll
        for (int j = 0; j < 4; ++j)
          acc[i][j] = __builtin_amdgcn_mfma_f32_16x16x32_bf16(af[i], bf[j], acc[i][j], 0, 0, 0);
    }
  }

  // epilogue: token s = quad*4+r, dh consecutive over lrow
  const int region = n0 >> 9;  // 0=Q, 1=K, 2=V (128 | 512 so no tile crosses)
  const float* bias = (region == 0) ? bq : ((region == 1) ? bkp : bv);
  const float mult = (region == 0) ? SCL : 1.0f;
  const int bb = m0 >> 13;
  const int nbbase = ((m0 & 8191) >> 4) + (wm >> 4);    // nb = nbbase + i
  const int nv0 = (n0 & 511) + wn;

  if (region < 2) {
    uint16_t* dst = (region == 0) ? Qp : Kp;
#pragma unroll
    for (int j = 0; j < 4; ++j) {
      int nl = nv0 + j * 16 + lrow;
      int hh = nl >> 6, dh = nl & 63;
      float bval = bias[nl];
      // addr = ((b*16+s)*8+h)*32768 + nb*64 + dh  (s = quad*4+r)
      size_t base = (size_t)bb * 4194304 + (size_t)hh * 32768 +
                    (size_t)nbbase * 64 + dh + (size_t)(quad * 4) * 262144;
#pragma unroll
      for (int i = 0; i < 4; ++i)
#pragma unroll
        for (int r = 0; r < 4; ++r)
          dst[base + (size_t)r * 262144 + (size_t)i * 64] =
              f2b((acc[i][j][r] + bval) * mult);
    }
  } else {
#pragma unroll
    for (int j = 0; j < 4; ++j) {
      int nl = nv0 + j * 16 + lrow;
      float bval = bias[nl];
#pragma unroll
      for (int i = 0; i < 4; ++i) {
        int tok = m0 + wm + i * 16 + quad * 4;
#pragma unroll
        for (int r = 0; r < 4; ++r)
          Vtmp[(size_t)(tok + r) * 512 + nl] = f2b(acc[i][j][r] + bval);
      }
    }
  }
}

// ---------------- fused block attention, S^T orientation, fixed-max softmax ----------------
// V is staged straight from Vtmp (token-major) into a tr-subtiled LDS layout and
// consumed with ds_read_b64_tr_b16 (T10); derivation in round-3 notes.
// r7 lesson (measured): launch_bounds(256,4) spills (VGPR clamped to 64, +172 MB
// scratch FETCH). r12 lesson (measured): 2-wave/128-thread blocks at 6/CU are
// neutral (waves/CU unchanged at 12). attn is latency-bound on its per-iteration
// serial chain (stage -> S -> exp2/pack -> Ps round-trip -> PV); packing levers
// don't move it. This 4-wave/(256,3) form is the verified optimum.
__global__ __launch_bounds__(256, 3) void attn_kernel(
    const uint16_t* __restrict__ Qp, const uint16_t* __restrict__ Kp,
    const uint16_t* __restrict__ Vtmp, float* __restrict__ out) {
  __shared__ uint16_t Ks[2][32 * 64];     // K tile, rows 128B, chunk pos = c ^ (r&7)
  __shared__ uint16_t Vs[2][32 * 64];     // V tile in tr-subtiled layout
  __shared__ uint16_t Ps[4][4][16 * 32];  // [wave][qs] P [q][kv], pos = c ^ ((q>>1)&3)

  int bx = blockIdx.x;
  const int qh = bx & 1; bx >>= 1;
  const int h = bx & 7; bx >>= 3;
  const int s = bx & 15;
  const int b = bx >> 4;

  const int tid = threadIdx.x;
  const int w = tid >> 6, lane = tid & 63;
  const int lrow = lane & 15, quad = lane >> 4;

  const size_t sh = (((size_t)b * 16 + s) * 8 + h);
  const uint16_t* Qb = Qp + (sh << 15);   // [512 nb][64 dh]
  const uint16_t* Kb = Kp + (sh << 15);   // [512 nb][64 dh]

  // V staging source: chunk c=tid covers LDS elems [8c,8c+8) of the tr layout.
  const int e_hi = tid >> 7, dtv = (tid >> 5) & 3, qv = (tid >> 3) & 3,
            jv = (tid >> 1) & 3, hbv = tid & 1;
  const int kvv = qv * 8 + e_hi * 4 + jv;
  const uint16_t* vsrc = Vtmp + ((size_t)b * Tsz + s) * 512 +
                         (size_t)kvv * 8192 + h * 64 + dtv * 16 + hbv * 8;
  const unsigned vs_base =
      (unsigned)(uintptr_t)(__attribute__((address_space(3))) const uint16_t*)&Vs[0][0];

  // Q B-fragments (persistent): 4 q-subtiles x 2 dh-chunks
  short8 qB[4][2];
  const int q0 = qh * 256 + w * 64;
#pragma unroll
  for (int qs = 0; qs < 4; ++qs) {
    const uint16_t* qp = Qb + (size_t)(q0 + qs * 16 + lrow) * 64;
    qB[qs][0] = *(const short8*)(qp + quad * 8);
    qB[qs][1] = *(const short8*)(qp + 32 + quad * 8);
  }

  float4f O[4][4] = {};                 // [dh tile][q subtile], C-layout (col=q)
  float l_acc[4] = {0.f, 0.f, 0.f, 0.f};

  const int kr = w * 8 + (lane >> 3);
  const int kcs = (lane & 7) ^ (kr & 7);

  const int sw = (lrow >> 1) & 3;
  const float4f negm = {-ATT_M, -ATT_M, -ATT_M, -ATT_M};

#define ATT_STAGE(buf, kv0_) do {                                             \
    gl_lds16(Kb + (size_t)((kv0_) + kr) * 64 + kcs * 8, &Ks[buf][w * 512]);   \
    gl_lds16(vsrc + (size_t)(kv0_) * 8192, &Vs[buf][w * 512]);                \
  } while (0)

  ATT_STAGE(0, 0);
  __syncthreads();

  for (int it = 0; it < 16; ++it) {
    const int cur = it & 1;
    if (it < 15) ATT_STAGE(cur ^ 1, (it + 1) * 32);  // prefetch hides under compute

    // ---- S-phase: K A-fragments, scores, exp2, pack into Ps ----
    {
      short8 kA[2][2];
#pragma unroll
      for (int kt = 0; kt < 2; ++kt) {
        int row = kt * 16 + lrow;
#pragma unroll
        for (int kc = 0; kc < 2; ++kc) {
          int cc = (kc * 4 + quad) ^ (row & 7);
          kA[kt][kc] = *(const short8*)(&Ks[cur][row * 64 + cc * 8]);
        }
      }
#pragma unroll
      for (int qs = 0; qs < 4; ++qs) {
        // C pre-loaded with -M: exp2 args come out of MFMA directly
        float4f c0 = negm, c1 = negm;
        __builtin_amdgcn_s_setprio(1);
        c0 = __builtin_amdgcn_mfma_f32_16x16x32_bf16(kA[0][0], qB[qs][0], c0, 0, 0, 0);
        c0 = __builtin_amdgcn_mfma_f32_16x16x32_bf16(kA[0][1], qB[qs][1], c0, 0, 0, 0);
        c1 = __builtin_amdgcn_mfma_f32_16x16x32_bf16(kA[1][0], qB[qs][0], c1, 0, 0, 0);
        c1 = __builtin_amdgcn_mfma_f32_16x16x32_bf16(kA[1][1], qB[qs][1], c1, 0, 0, 0);
        __builtin_amdgcn_s_setprio(0);

        float p00 = __builtin_amdgcn_exp2f(c0[0]);
        float p01 = __builtin_amdgcn_exp2f(c0[1]);
        float p02 = __builtin_amdgcn_exp2f(c0[2]);
        float p03 = __builtin_amdgcn_exp2f(c0[3]);
        float p10 = __builtin_amdgcn_exp2f(c1[0]);
        float p11 = __builtin_amdgcn_exp2f(c1[1]);
        float p12 = __builtin_amdgcn_exp2f(c1[2]);
        float p13 = __builtin_amdgcn_exp2f(c1[3]);
        l_acc[qs] += ((p00 + p01) + (p02 + p03)) + ((p10 + p11) + (p12 + p13));

        uint32_t d0 = pk2t(p00, p01), d1 = pk2t(p02, p03);
        uint32_t d2 = pk2t(p10, p11), d3 = pk2t(p12, p13);
        uint16_t* Psq = Ps[w][qs];
        int half = (quad & 1) * 4;
        *(uint2*)(Psq + lrow * 32 + (((quad >> 1)) ^ sw) * 8 + half) = make_uint2(d0, d1);
        *(uint2*)(Psq + lrow * 32 + ((2 + (quad >> 1)) ^ sw) * 8 + half) = make_uint2(d2, d3);
      }
    }

    // ---- PV-phase: V^T A-fragments via hardware transpose read ----
    {
      short4v t0, t1, t2, t3, t4, t5, t6, t7;
      unsigned vaddr = vs_base + (cur << 12) + (lane << 3);
      asm volatile(
          "ds_read_b64_tr_b16 %0, %8\n\t"
          "ds_read_b64_tr_b16 %1, %8 offset:2048\n\t"
          "ds_read_b64_tr_b16 %2, %8 offset:512\n\t"
          "ds_read_b64_tr_b16 %3, %8 offset:2560\n\t"
          "ds_read_b64_tr_b16 %4, %8 offset:1024\n\t"
          "ds_read_b64_tr_b16 %5, %8 offset:3072\n\t"
          "ds_read_b64_tr_b16 %6, %8 offset:1536\n\t"
          "ds_read_b64_tr_b16 %7, %8 offset:3584\n\t"
          "s_waitcnt lgkmcnt(0)"
          : "=&v"(t0), "=&v"(t1), "=&v"(t2), "=&v"(t3),
            "=&v"(t4), "=&v"(t5), "=&v"(t6), "=&v"(t7)
          : "v"(vaddr));
      __builtin_amdgcn_sched_barrier(0);
      short8 vA[4];
      vA[0] = __builtin_shufflevector(t0, t1, 0, 1, 2, 3, 4, 5, 6, 7);
      vA[1] = __builtin_shufflevector(t2, t3, 0, 1, 2, 3, 4, 5, 6, 7);
      vA[2] = __builtin_shufflevector(t4, t5, 0, 1, 2, 3, 4, 5, 6, 7);
      vA[3] = __builtin_shufflevector(t6, t7, 0, 1, 2, 3, 4, 5, 6, 7);
#pragma unroll
      for (int qs = 0; qs < 4; ++qs) {
        short8 pB = *(const short8*)(Ps[w][qs] + lrow * 32 + (quad ^ sw) * 8);
        __builtin_amdgcn_s_setprio(1);
#pragma unroll
        for (int dt = 0; dt < 4; ++dt)
          O[dt][qs] = __builtin_amdgcn_mfma_f32_16x16x32_bf16(vA[dt], pB, O[dt][qs], 0, 0, 0);
        __builtin_amdgcn_s_setprio(0);
      }
    }

    if (it < 15) __syncthreads();  // own stage landed (vmcnt) + all waves done with cur
  }
#undef ATT_STAGE

  // epilogue: reduce l across quads (kv partials), normalize, write fp32
#pragma unroll
  for (int qs = 0; qs < 4; ++qs) {
    float l = l_acc[qs];
    l += __shfl_xor(l, 16);
    l += __shfl_xor(l, 32);
    float inv = 1.0f / l;
    int qg = q0 + qs * 16 + lrow;   // nb index of this lane's q column
    float* op = out + ((size_t)b * Tsz + (size_t)qg * 16 + s) * Dsz + h * 64;
#pragma unroll
    for (int dt = 0; dt < 4; ++dt) {
      float4 vv;
      vv.x = O[dt][qs][0] * inv; vv.y = O[dt][qs][1] * inv;
      vv.z = O[dt][qs][2] * inv; vv.w = O[dt][qs][3] * inv;
      *(float4*)(op + dt * 16 + quad * 4) = vv;
    }
  }
}

// ---------------- launch ----------------
extern "C" void kernel_launch(void* const* d_in, const int* in_sizes, int n_in,
                              void* d_out, int out_size, void* d_ws, size_t ws_size,
                              hipStream_t stream) {
  const float* x  = (const float*)d_in[0];
  const float* Wq = (const float*)d_in[1];
  const float* bq = (const float*)d_in[2];
  const float* Wk = (const float*)d_in[3];
  const float* bk = (const float*)d_in[4];
  const float* Wv = (const float*)d_in[5];
  const float* bv = (const float*)d_in[6];
  float* out = (float*)d_out;

  // workspace: Qp | Kp | Vtmp | xb | wc
  uint16_t* Qp   = (uint16_t*)d_ws;
  uint16_t* Kp   = Qp + (size_t)16777216;
  uint16_t* Vtmp = Kp + (size_t)16777216;
  uint16_t* xb   = Vtmp + (size_t)16777216;
  uint16_t* wc   = xb + (size_t)16777216;

  hipLaunchKernelGGL(cvt_kernel, dim3(XBLK + NQKV * Dsz / 1024), dim3(256), 0, stream,
                     x, Wq, Wk, Wv, xb, wc);
  hipLaunchKernelGGL(gemm_qkv, dim3((MROWS / BM) * (NQKV / BN)), dim3(256), 0, stream,
                     xb, wc, bq, bk, bv, Qp, Kp, Vtmp);
  hipLaunchKernelGGL(attn_kernel, dim3(Bsz * BSn * Hn * 2), dim3(256), 0, stream,
                     Qp, Kp, Vtmp, out);
}